// Round 6
// baseline (263.505 us; speedup 1.0000x reference)
//
#include <hip/hip_runtime.h>

// MHA: B=2, S=2048, D=1024, H=16, DK=64. I/O bf16 (harness-confirmed R4);
// dual fp32 path retained via runtime detect. mask int32.
//
// Pipeline (ws 16 MB; d_out doubles as V scratch):
//   0) detect: classify d_in[0] bf16 vs fp32 -> flag in ws
//   1) gemmk<128,64,0>: Q/K/V proj y = x @ W^T (one launch, z selects).
//   2) attn: flash, 128 q-rows/block (32/wave, 2 q-tiles), 64 keys/iter.
//   3) gemmk<64,64,1>: out = ctx @ Wo^T -> d_out.
//
// MFMA 16x16x32 bf16 layouts (verified):
//   A: lane holds A[m=lane&15][k=(lane>>4)*8+j]
//   B: lane holds B[k=(lane>>4)*8+j][n=lane&15]
//   C/D: col=lane&15, row=(lane>>4)*4+reg
//
// R4: no u16/bf16 punning (TBAA reorder -> NaN).
// R5/R6: direct global K/V and VGPR-roundtrip staging = latency bound.
// R8 REGRESSION: dual MFMA orientation in gemm K-loop.
// R9: BK=64 gemms win over BK=128.
// R10 FAILED: ds_read_b64_tr_b16 gather model wrong.
// R11: swapped-MFMA packed-P attn 85.6 -> 75.6 us.
// R12 REGRESSION: dbuf with __syncthreads (still drains vmcnt to 0).
// R13 FLAT (falsifier fired): 2x occupancy, same time -> stall is the
//   CORRELATED vmcnt(0) drain at every K-step barrier; TLP can't hide it.
// R14 (untested: container failed twice): T4 counted-vmcnt depth-3
//   staging in all three kernels. vmcnt audit re-done: no deadlock path;
//   bounds OK.
// R15 (this round): R14 resubmitted with sync HARDENED, no schedule
//   changes: (1) s_barrier via inline asm with "memory" clobber (the
//   plain builtin is not a compiler fence -> LDS reads of buf[cur] could
//   sink past the barrier into stage(t+2)'s overwrite, m152-class race);
//   (2) sched_barrier(0) after each counted vmcnt (rule #18);
//   (3) attn BiasL prologue now syncs via fenced barrier (cross-wave
//   visibility), not just own-wave lgkmcnt.

typedef __bf16 bf16x8 __attribute__((ext_vector_type(8)));
typedef __bf16 bf16x4 __attribute__((ext_vector_type(4)));
typedef float f32x4 __attribute__((ext_vector_type(4)));

#define B_ 2
#define S_ 2048
#define D_ 1024
#define H_ 16
#define DK_ 64
#define QSCALE 0.18033688011112042f  // 0.125 * log2(e)

// fenced barrier: real s_barrier + compiler memory fence both sides
__device__ __forceinline__ void barrier_fenced() {
  asm volatile("s_barrier" ::: "memory");
}

template <int N>
__device__ __forceinline__ void wait_vmcnt() {
  if constexpr (N == 0) asm volatile("s_waitcnt vmcnt(0)" ::: "memory");
  else if constexpr (N == 4) asm volatile("s_waitcnt vmcnt(4)" ::: "memory");
  else if constexpr (N == 6) asm volatile("s_waitcnt vmcnt(6)" ::: "memory");
  else static_assert(N == 0 || N == 4 || N == 6, "unsupported vmcnt");
  __builtin_amdgcn_sched_barrier(0);  // rule #18: pin motion at the wait
}

// ---------------------------------------------------------------------------
__global__ void detect_dtype(const unsigned int* __restrict__ qw,
                             int* __restrict__ flag) {
  int cnt = 0;
#pragma unroll
  for (int i = 0; i < 4; ++i) {
    unsigned int w = qw[threadIdx.x + 64 * i];
    int e = (w >> 7) & 0xFF;
    cnt += (e >= 100 && e <= 140) ? 1 : 0;
  }
#pragma unroll
  for (int off = 32; off > 0; off >>= 1) cnt += __shfl_down(cnt, off, 64);
  if (threadIdx.x == 0) *flag = (cnt >= 128) ? 0 : 1;
}

__device__ __forceinline__ bf16x8 load8cvt(const void* base, size_t eoff,
                                           bool f32) {
  if (!f32) return *(const bf16x8*)((const __bf16*)base + eoff);
  const float* p = (const float*)base + eoff;
  bf16x8 r;
#pragma unroll
  for (int j = 0; j < 8; ++j) r[j] = (__bf16)p[j];
  return r;
}

// async 16B global -> LDS (lds dest = wave-uniform base + lane*16)
__device__ __forceinline__ void async_cp16(const __bf16* g, __bf16* l) {
  __builtin_amdgcn_global_load_lds(
      (const __attribute__((address_space(1))) unsigned int*)g,
      (__attribute__((address_space(3))) unsigned int*)l, 16, 0, 0);
}

// ---------------------------------------------------------------------------
// GEMM (R14/R15): C[M,N] = X[M,K] @ W[N,K]^T, TM x TN tile, BK=64, 3 LDS
// buffers, counted-vmcnt pipelined K-loop (bf16 path). NCH = cp16s per
// wave per tile; wait vmcnt(NCH) keeps tile t+1 in flight, forces tile t.
// Per iter: {vmcnt(NCH) [0 last] -> fenced s_barrier -> stage(t+2) ->
// compute(t)}. Hazard: stage(t+2) overwrites buf read at t-1; issued
// strictly after the barrier all waves reach only post-read.
// LDS rows [*][64], 16B chunks XOR-swizzled (phys j = jl ^ (row&7)).
// f32 fallback: old single-buffer 2-barrier loop (correct, cold path).
// ---------------------------------------------------------------------------
template <int TM, int TN, int MODE>
__global__ __launch_bounds__(256) void gemmk(
    const void* X0, const void* X1, const void* X2,
    const void* W0, const void* W1, const void* W2,
    void* O0, void* O1, void* O2, const int* __restrict__ dflag) {
  constexpr int Kd = 1024, Nd = 1024;
  constexpr int MI = TM / 32;
  constexpr int NI = TN / 32;
  constexpr int ACH = TM / 32;
  constexpr int BCH = TN / 32;
  constexpr int NCH = ACH + BCH;  // cp16 per wave per K-tile
  const void* X = (blockIdx.z == 0) ? X0 : (blockIdx.z == 1 ? X1 : X2);
  const void* W = (blockIdx.z == 0) ? W0 : (blockIdx.z == 1 ? W1 : W2);
  void* O = (blockIdx.z == 0) ? O0 : (blockIdx.z == 1 ? O1 : O2);
  const bool f32io = (*dflag != 0);

  __shared__ __attribute__((aligned(16))) __bf16 As[3][TM * 64];
  __shared__ __attribute__((aligned(16))) __bf16 Bs[3][TN * 64];

  const int m0 = blockIdx.x * TM;
  const int n0 = blockIdx.y * TN;
  const int t = threadIdx.x;
  const int lane = t & 63, wave = t >> 6;
  const int l15 = lane & 15, quad = lane >> 4;
  const int wm = (wave >> 1) * (TM / 2);
  const int wn = (wave & 1) * (TN / 2);

  const __bf16* gA[ACH];
  int ldsAoff[ACH];
#pragma unroll
  for (int i = 0; i < ACH; ++i) {
    int c = (wave * ACH + i) * 64 + lane;
    int row = c >> 3, j = c & 7;
    int jl = j ^ (row & 7);
    ldsAoff[i] = (wave * ACH + i) * 512;
    if (MODE == 0) {
      gA[i] = (const __bf16*)X + (size_t)(m0 + row) * Kd + jl * 8;
    } else {
      int gm = m0 + row;
      gA[i] = (const __bf16*)X + (size_t)(gm >> 11) * (H_ * S_ * DK_) +
              (size_t)(gm & (S_ - 1)) * DK_ + jl * 8;
    }
  }
  const __bf16* gB[BCH];
  int ldsBoff[BCH];
#pragma unroll
  for (int i = 0; i < BCH; ++i) {
    int c = (wave * BCH + i) * 64 + lane;
    int row = c >> 3, j = c & 7;
    int jl = j ^ (row & 7);
    ldsBoff[i] = (wave * BCH + i) * 512;
    gB[i] = (const __bf16*)W + (size_t)(n0 + row) * Kd + jl * 8;
  }

  auto stage_tile = [&](int k0, int bsel) {
    if (MODE == 0) {
#pragma unroll
      for (int i = 0; i < ACH; ++i)
        async_cp16(gA[i] + k0, &As[bsel][ldsAoff[i]]);
    } else {
      const size_t koff = (size_t)(k0 >> 6) * (S_ * DK_);
#pragma unroll
      for (int i = 0; i < ACH; ++i)
        async_cp16(gA[i] + koff, &As[bsel][ldsAoff[i]]);
    }
#pragma unroll
    for (int i = 0; i < BCH; ++i)
      async_cp16(gB[i] + k0, &Bs[bsel][ldsBoff[i]]);
  };

  f32x4 acc[MI][NI] = {};

  auto compute_tile = [&](const __bf16* Ab, const __bf16* Bb) {
#pragma unroll
    for (int h = 0; h < 2; ++h) {
      bf16x8 af[MI], bfr[NI];
#pragma unroll
      for (int mi = 0; mi < MI; ++mi) {
        int row = wm + mi * 16 + l15;
        af[mi] = *(const bf16x8*)&Ab[row * 64 +
                                     (((h * 4 + quad) ^ (row & 7)) << 3)];
      }
#pragma unroll
      for (int ni = 0; ni < NI; ++ni) {
        int row = wn + ni * 16 + l15;
        bfr[ni] = *(const bf16x8*)&Bb[row * 64 +
                                      (((h * 4 + quad) ^ (row & 7)) << 3)];
      }
#pragma unroll
      for (int mi = 0; mi < MI; ++mi)
#pragma unroll
        for (int ni = 0; ni < NI; ++ni)
          acc[mi][ni] = __builtin_amdgcn_mfma_f32_16x16x32_bf16(
              af[mi], bfr[ni], acc[mi][ni], 0, 0, 0);
    }
  };

  if (!f32io) {
    // ---- pipelined bf16 path: depth-3, counted vmcnt ----
    stage_tile(0, 0);
    stage_tile(64, 1);
    int cur = 0;
    for (int kt = 0; kt < 16; ++kt) {
      if (kt == 15) wait_vmcnt<0>();
      else          wait_vmcnt<NCH>();
      barrier_fenced();
      if (kt < 14) {
        int nb = cur + 2; if (nb >= 3) nb -= 3;
        stage_tile((kt + 2) * 64, nb);
      }
      compute_tile(&As[cur][0], &Bs[cur][0]);
      cur = (cur == 2) ? 0 : cur + 1;
    }
  } else {
    // ---- f32 fallback: single buffer, 2-barrier loop ----
    for (int k0 = 0; k0 < Kd; k0 += 64) {
      __syncthreads();
#pragma unroll
      for (int i = 0; i < TM / 32; ++i) {
        int c = t + 256 * i;
        int row = c >> 3, j = c & 7;
        int jl = j ^ (row & 7);
        bf16x8 xv;
        if (MODE == 0) {
          xv = load8cvt(X, (size_t)(m0 + row) * Kd + k0 + jl * 8, true);
        } else {
          int gm = m0 + row, gk = k0 + jl * 8;
          xv = *(const bf16x8*)((const __bf16*)X +
                ((((size_t)(gm >> 11) * H_ + (gk >> 6)) * S_) +
                 (gm & (S_ - 1))) * DK_ + (gk & (DK_ - 1)));
        }
        *(bf16x8*)&As[0][row * 64 + j * 8] = xv;
      }
#pragma unroll
      for (int i = 0; i < TN / 32; ++i) {
        int c = t + 256 * i;
        int row = c >> 3, j = c & 7;
        int jl = j ^ (row & 7);
        bf16x8 wv = load8cvt(W, (size_t)(n0 + row) * Kd + k0 + jl * 8, true);
        *(bf16x8*)&Bs[0][row * 64 + j * 8] = wv;
      }
      __syncthreads();
      compute_tile(&As[0][0], &Bs[0][0]);
    }
  }

  const float oscale = (MODE == 0 && blockIdx.z == 0) ? QSCALE : 1.0f;
#pragma unroll
  for (int mi = 0; mi < MI; ++mi) {
#pragma unroll
    for (int ni = 0; ni < NI; ++ni) {
      int mbase = m0 + wm + mi * 16 + quad * 4;
      int n = n0 + wn + ni * 16 + l15;
      if (MODE == 0 && blockIdx.z == 2) {
        int b = mbase >> 11, sb = mbase & (S_ - 1);
        int h = n >> 6, dk = n & (DK_ - 1);
        bf16x4 pk;
#pragma unroll
        for (int r = 0; r < 4; ++r) pk[r] = (__bf16)acc[mi][ni][r];
        *(bf16x4*)&((__bf16*)O)[((size_t)(b * H_ + h) * DK_ + dk) * S_ + sb] = pk;
      } else {
#pragma unroll
        for (int r = 0; r < 4; ++r) {
          int m = mbase + r;
          float val = acc[mi][ni][r] * oscale;
          if (MODE == 0) {
            int b = m >> 11, s = m & (S_ - 1);
            int h = n >> 6, dk = n & (DK_ - 1);
            ((__bf16*)O)[((size_t)(b * H_ + h) * S_ + s) * DK_ + dk] = (__bf16)val;
          } else {
            size_t idx = (size_t)m * Nd + n;
            if (f32io) ((float*)O)[idx] = val;
            else       ((__bf16*)O)[idx] = (__bf16)val;
          }
        }
      }
    }
  }
}

// ---------------------------------------------------------------------------
// Flash attention (R14/R15): R11 fragment/P paths verbatim; staging depth-3
// counted-vmcnt (K/V bufs x3); mask precomputed into an LDS f32 bias table
// in the prologue (bias reads ride lgkm, keeping the vmcnt stream pure =
// 4 cp16/wave/tile). Per iter: {vmcnt(4) [0 last] -> fenced s_barrier ->
// stage(t+2) -> scores -> exp/P -> PV}. T5 setprio around MFMA clusters.
// grid 512, LDS 72KB -> 2 blocks/CU.
// ---------------------------------------------------------------------------
__global__ __launch_bounds__(256, 2) void attn(
    const __bf16* Qh, const __bf16* __restrict__ Kh,
    const __bf16* __restrict__ Vt, const int* __restrict__ mask,
    __bf16* Out) {
  __shared__ __attribute__((aligned(16))) __bf16 Ks[3][4096];
  __shared__ __attribute__((aligned(16))) __bf16 Vs[3][4096];
  __shared__ __attribute__((aligned(16))) __bf16 P[4][2048];  // wave: 2 x [16][64]
  __shared__ __attribute__((aligned(16))) float BiasL[2048];

  const int t = threadIdx.x;
  const int lane = t & 63, wave = t >> 6;
  const int l15 = lane & 15, quad = lane >> 4;
  const int qb = blockIdx.x & 15;   // 16 q-blocks of 128
  const int bh = blockIdx.x >> 4;   // b*H + h
  const int b = bh >> 4;
  const int q0 = qb * 128 + wave * 32;

  const __bf16* Q = Qh + (size_t)bh * S_ * DK_;
  const __bf16* K = Kh + (size_t)bh * S_ * DK_;
  const __bf16* V = Vt + (size_t)bh * DK_ * S_;   // [dk][s]
  const int* mk = mask + b * S_;

  bf16x8 qf[2][2];
#pragma unroll
  for (int qt = 0; qt < 2; ++qt) {
    qf[qt][0] = *(const bf16x8*)&Q[(size_t)(q0 + qt * 16 + l15) * DK_ + quad * 8];
    qf[qt][1] = *(const bf16x8*)&Q[(size_t)(q0 + qt * 16 + l15) * DK_ + 32 + quad * 8];
  }

  f32x4 o[2][4] = {};
  float lsum[2] = {0.f, 0.f};

  // loop-invariant P element offsets (within P[wave], before qt*1024)
  int pst[4], prd[2];
#pragma unroll
  for (int tt = 0; tt < 4; ++tt)
    pst[tt] = l15 * 64 + (((tt * 2 + (quad >> 1)) ^ (l15 & 7)) << 3) +
              (quad & 1) * 4;
#pragma unroll
  for (int kt = 0; kt < 2; ++kt)
    prd[kt] = l15 * 64 + (((kt * 4 + quad) ^ (l15 & 7)) << 3);

  auto stage_kv = [&](int key0, int bsel) {
#pragma unroll
    for (int i = 0; i < 2; ++i) {
      int l = wave * 128 + i * 64 + lane;
      int row = l >> 3, jg = (l & 7) ^ (row & 7);
      async_cp16(K + (size_t)(key0 + row) * DK_ + jg * 8,
                 &Ks[bsel][(size_t)(l - lane) * 8]);
      async_cp16(V + (size_t)row * S_ + key0 + jg * 8,
                 &Vs[bsel][(size_t)(l - lane) * 8]);
    }
  };

  // prologue: bias table (LDS, lgkm path) + first two K/V tiles
#pragma unroll
  for (int i = 0; i < 8; ++i) {
    int key = i * 256 + t;
    BiasL[key] = mk[key] ? 0.f : -1e9f;
  }
  stage_kv(0, 0);
  stage_kv(64, 1);
  // drain own-wave LDS writes, then fenced barrier for cross-wave
  // visibility of BiasL before any wave reads it in the loop.
  asm volatile("s_waitcnt lgkmcnt(0)" ::: "memory");
  barrier_fenced();

  int cur = 0;
  for (int it = 0; it < 32; ++it) {
    const int kb = it << 6;
    if (it == 31) wait_vmcnt<0>();
    else          wait_vmcnt<4>();
    barrier_fenced();
    if (it < 30) {
      int nb = cur + 2; if (nb >= 3) nb -= 3;
      stage_kv(kb + 128, nb);
    }

    // ---- scores (SWAPPED): s[key=quad*4+r][q=l15]; K frags shared ----
    const __bf16* ks = &Ks[cur][0];
    f32x4 s[2][4];
    __builtin_amdgcn_s_setprio(1);
#pragma unroll
    for (int tt = 0; tt < 4; ++tt) {
      int row = tt * 16 + l15;
      bf16x8 kf0 = *(const bf16x8*)&ks[row * 64 + ((quad ^ (l15 & 7)) << 3)];
      bf16x8 kf1 = *(const bf16x8*)&ks[row * 64 + (((4 + quad) ^ (l15 & 7)) << 3)];
      f32x4 z = *(const f32x4*)&BiasL[kb + tt * 16 + quad * 4];
      f32x4 z0 = __builtin_amdgcn_mfma_f32_16x16x32_bf16(kf0, qf[0][0], z, 0, 0, 0);
      s[0][tt] = __builtin_amdgcn_mfma_f32_16x16x32_bf16(kf1, qf[0][1], z0, 0, 0, 0);
      f32x4 z1 = __builtin_amdgcn_mfma_f32_16x16x32_bf16(kf0, qf[1][0], z, 0, 0, 0);
      s[1][tt] = __builtin_amdgcn_mfma_f32_16x16x32_bf16(kf1, qf[1][1], z1, 0, 0, 0);
    }
    __builtin_amdgcn_s_setprio(0);

    // ---- V fragments (issue while exp phase runs; shared by q-tiles) ----
    const __bf16* vs = &Vs[cur][0];
    bf16x8 vf[2][4];
#pragma unroll
    for (int kt = 0; kt < 2; ++kt)
#pragma unroll
      for (int nt = 0; nt < 4; ++nt) {
        int dk = nt * 16 + l15;
        vf[kt][nt] =
            *(const bf16x8*)&vs[dk * 64 + (((kt * 4 + quad) ^ (l15 & 7)) << 3)];
      }

    // ---- exp2 + packed P store: one b64 per (qt,tt) ----
#pragma unroll
    for (int qt = 0; qt < 2; ++qt) {
      float acc = 0.f;
#pragma unroll
      for (int tt = 0; tt < 4; ++tt) {
        bf16x4 pk;
#pragma unroll
        for (int r = 0; r < 4; ++r) {
          float e = __builtin_exp2f(s[qt][tt][r]);   // Q carries 0.125*log2e
          acc += e;
          pk[r] = (__bf16)e;
        }
        *(bf16x4*)&P[wave][qt * 1024 + pst[tt]] = pk;
      }
      lsum[qt] += acc;
    }

    asm volatile("" ::: "memory");  // pin P stores above the P reads (TBAA)

    // ---- PV: P read back as A-frag via b128; V frags shared ----
    __builtin_amdgcn_s_setprio(1);
#pragma unroll
    for (int qt = 0; qt < 2; ++qt)
#pragma unroll
      for (int kt = 0; kt < 2; ++kt) {
        bf16x8 pf = *(const bf16x8*)&P[wave][qt * 1024 + prd[kt]];
#pragma unroll
        for (int nt = 0; nt < 4; ++nt)
          o[qt][nt] = __builtin_amdgcn_mfma_f32_16x16x32_bf16(
              pf, vf[kt][nt], o[qt][nt], 0, 0, 0);
      }
    __builtin_amdgcn_s_setprio(0);

    cur = (cur == 2) ? 0 : cur + 1;
  }

  // lsum finish: all keys of a q-row live in lanes with same l15
#pragma unroll
  for (int qt = 0; qt < 2; ++qt) {
    float v = lsum[qt];
    v += __shfl_xor(v, 16, 64);
    v += __shfl_xor(v, 32, 64);
    lsum[qt] = v;  // every lane: sum for q = l15 (of tile qt)
  }

#pragma unroll
  for (int qt = 0; qt < 2; ++qt) {
    float rinv[4];
#pragma unroll
    for (int r = 0; r < 4; ++r)
      rinv[r] = 1.0f / __shfl(lsum[qt], quad * 4 + r, 64);
#pragma unroll
    for (int nt = 0; nt < 4; ++nt)
#pragma unroll
      for (int r = 0; r < 4; ++r) {
        int qrow = q0 + qt * 16 + quad * 4 + r;
        Out[(size_t)bh * S_ * DK_ + (size_t)qrow * DK_ + nt * 16 + l15] =
            (__bf16)(o[qt][nt][r] * rinv[r]);
      }
  }
}

extern "C" void kernel_launch(void* const* d_in, const int* in_sizes, int n_in,
                              void* d_out, int out_size, void* d_ws, size_t ws_size,
                              hipStream_t stream) {
  const void* q = d_in[0];
  const void* k = d_in[1];
  const void* v = d_in[2];
  const int* mask = (const int*)d_in[3];
  const void* Wq = d_in[4];
  const void* Wk = d_in[5];
  const void* Wv = d_in[6];
  const void* Wo = d_in[7];

  const size_t NE = (size_t)B_ * H_ * S_ * DK_;  // 4,194,304 elems
  __bf16* Qh = (__bf16*)d_ws;                    // ws[0 : 8M)  -> becomes ctx
  __bf16* Kh = Qh + NE;                          // ws[8M : 16M)
  int* dflag = (int*)((char*)d_ws + 2 * NE * sizeof(__bf16));
  __bf16* Vt = (__bf16*)d_out;                   // scratch; dead before final write

  detect_dtype<<<1, 64, 0, stream>>>((const unsigned int*)q, dflag);
  dim3 g1(32, 16, 3);
  gemmk<128, 64, 0><<<g1, 256, 0, stream>>>(q, k, v, Wq, Wk, Wv, Qh, Kh, Vt,
                                            dflag);
  attn<<<512, 256, 0, stream>>>(Qh, Kh, Vt, mask, Qh);
  dim3 g2(64, 16, 1);
  gemmk<64, 64, 1><<<g2, 256, 0, stream>>>(Qh, Qh, Qh, Wo, Wo, Wo, d_out,
                                           d_out, d_out, dflag);
}